// Round 9
// baseline (273.897 us; speedup 1.0000x reference)
//
#include <hip/hip_runtime.h>
#include <hip/hip_bf16.h>
#include <math.h>

#define BB   16
#define SS   2048
#define HH   768
#define MAXN 400
#define LBL  97
#define MIDD 768
#define KTOT 1536   // 2*HH

#define K2_XTILES 25                      // ceil(400/16)
#define W1S_JOBS  (192 * 768)             // [k/8][col] b128 units per plane
#define K1_RT     7                       // ceil(400/64)
#define K1_GROUPS (K1_RT * BB)            // 112
#define K1_SPLIT  4                       // split-K ways (K chunk = 384)
#define K1_UNITS  (K1_GROUPS * K1_SPLIT)  // 448
#define K1_BLOCKS (K1_UNITS * 6)          // 2688
#define K1_KI     (KTOT / 32 / K1_SPLIT)  // 12 k-iters per block
#define HSTRIDE   ((size_t)BB * MAXN * MIDD)   // one h buffer, floats

typedef __attribute__((ext_vector_type(8)))  __bf16 bf16x8;
typedef __attribute__((ext_vector_type(16))) float  f32x16;

// ---------------------------------------------------------------------------
// K0: split W1 (f32 [1536][768]) into hi/lo bf16 planes, layout [k>>3][col][8].
// ---------------------------------------------------------------------------
__global__ __launch_bounds__(256)
void k0_split(const float* __restrict__ W1, ushort* __restrict__ hi,
              ushort* __restrict__ lo)
{
    const int job = blockIdx.x * 256 + threadIdx.x;   // 0..147455
    if (job >= W1S_JOBS) return;
    const int g   = job / 768;                        // k-octet 0..191
    const int col = job - g * 768;
    bf16x8 hv, lv;
    #pragma unroll
    for (int j = 0; j < 8; ++j) {
        const float f = W1[(size_t)(g * 8 + j) * MIDD + col];
        const __bf16 hb = (__bf16)f;                  // RNE
        hv[j] = hb;
        lv[j] = (__bf16)(f - (float)hb);
    }
    ((bf16x8*)hi)[job] = hv;
    ((bf16x8*)lo)[job] = lv;
}

// ---------------------------------------------------------------------------
// K1: fused gather + GEMM1 via bf16 3-pass split MFMA, 4-way split-K.
// nbuf==4: each split stores its partial to h[s*HSTRIDE] (plain coalesced
// stores, NO atomics). nbuf==1: legacy atomicAdd into zeroed h[0] (fallback
// when ws_size is too small). Bias+relu applied in K2.
// ---------------------------------------------------------------------------
__global__ __launch_bounds__(256, 2)
void k1_gemm1(const float* __restrict__ outs, const int* __restrict__ rels_pos,
              const ushort* __restrict__ w1hi, const ushort* __restrict__ w1lo,
              float* __restrict__ h, int nbuf)
{
    // --- swizzled decode: unit u=(g,s) gets its 6 n-tiles on one XCD ---
    const int gid = blockIdx.x;
    const int idx = gid >> 3;
    const int u   = (gid & 7) + 8 * (idx / 6);        // 0..447
    const int m   = idx % 6;                          // n-tile
    const int g   = u >> 2;                           // 0..111 (rt,b group)
    const int s   = u & 3;                            // split-K index
    const int rt  = g % K1_RT;
    const int b   = g / K1_RT;
    const int n0  = m * 128;
    const int i0  = rt * 64;
    const int ks  = s * K1_KI;                        // first k-iter (abs)

    const int num = rels_pos[2 * b + 1];
    if (i0 >= num) return;
    const int start = rels_pos[2 * b + 0];

    __shared__ __bf16 Ah[4][64][8];      // 4 KB
    __shared__ __bf16 Al[4][64][8];      // 4 KB
    __shared__ __bf16 Bh[4][128][8];     // 8 KB
    __shared__ __bf16 Bl[4][128][8];     // 8 KB

    const int tid = threadIdx.x;

    // --- A staging map: thread = (row 0..63, k-octet 0..3) ---
    const int srow = tid & 63;
    const int sg   = tid >> 6;
    const int irow = i0 + srow;                       // clamped reads, safe
    int p1 = start + 4 * irow;     p1 = min(max(p1, 0), SS - 1);
    int p2 = start + 4 * irow + 2; p2 = min(max(p2, 0), SS - 1);
    const float* arow1 = outs + (size_t)(b * SS + p1) * HH;
    const float* arow2 = outs + (size_t)(b * SS + p2) * HH;

    // --- B staging map: thread covers (col 0..127) x 2 k-octets ---
    const int bc  = tid & 127;
    const int bg1 = tid >> 7;                         // 0,1
    const int bg2 = 2 + (tid >> 7);                   // 2,3
    const bf16x8* WH = (const bf16x8*)w1hi;
    const bf16x8* WL = (const bf16x8*)w1lo;

    // --- wave map: 2x2 waves of 32x64 ---
    const int lane = tid & 63;
    const int wid  = tid >> 6;
    const int wr   = wid >> 1;
    const int wc   = wid & 1;
    const int l31  = lane & 31;
    const int lhi  = lane >> 5;

    f32x16 acc[2];
    #pragma unroll
    for (int n = 0; n < 2; ++n)
        #pragma unroll
        for (int j = 0; j < 16; ++j) acc[n][j] = 0.f;

    // ---- 2-deep prefetch register sets (named, no dynamic indexing) ----
    float4 aU0, aV0, aU1, aV1;
    bf16x8 pB00, pB01, pB02, pB03, pB10, pB11, pB12, pB13;

    #define K1_LOAD(AU, AV, P0, P1_, P2_, P3_, KT)                            \
        {                                                                     \
            const int k0 = (KT) * 32;                                         \
            const int k  = k0 + sg * 8;                                       \
            const float* sp = (k < HH) ? (arow1 + k) : (arow2 + (k - HH));    \
            AU = *(const float4*)(sp);                                        \
            AV = *(const float4*)(sp + 4);                                    \
            const size_t base = (size_t)(k0 >> 3) * 768 + n0 + bc;            \
            const size_t i1 = base + (size_t)bg1 * 768;                       \
            const size_t i2 = base + (size_t)bg2 * 768;                       \
            P0 = WH[i1]; P1_ = WL[i1]; P2_ = WH[i2]; P3_ = WL[i2];            \
        }

    #define K1_STAGE(AU, AV, P0, P1_, P2_, P3_)                               \
        {                                                                     \
            const float fa[8] = {AU.x, AU.y, AU.z, AU.w,                      \
                                 AV.x, AV.y, AV.z, AV.w};                     \
            bf16x8 ah, al;                                                    \
            _Pragma("unroll")                                                 \
            for (int j = 0; j < 8; ++j) {                                     \
                const __bf16 hb = (__bf16)fa[j];                              \
                ah[j] = hb;                                                   \
                al[j] = (__bf16)(fa[j] - (float)hb);                          \
            }                                                                 \
            *(bf16x8*)&Ah[sg][srow][0] = ah;                                  \
            *(bf16x8*)&Al[sg][srow][0] = al;                                  \
            *(bf16x8*)&Bh[bg1][bc][0]  = P0;                                  \
            *(bf16x8*)&Bl[bg1][bc][0]  = P1_;                                 \
            *(bf16x8*)&Bh[bg2][bc][0]  = P2_;                                 \
            *(bf16x8*)&Bl[bg2][bc][0]  = P3_;                                 \
        }

    #define K1_MFMA()                                                         \
        _Pragma("unroll")                                                     \
        for (int ss = 0; ss < 2; ++ss) {                                      \
            const int kg   = 2 * ss + lhi;                                    \
            const int arow = wr * 32 + l31;                                   \
            const bf16x8 xh = *(const bf16x8*)&Ah[kg][arow][0];               \
            const bf16x8 xl = *(const bf16x8*)&Al[kg][arow][0];               \
            _Pragma("unroll")                                                 \
            for (int n = 0; n < 2; ++n) {                                     \
                const int bcol = wc * 64 + n * 32 + l31;                      \
                const bf16x8 yh = *(const bf16x8*)&Bh[kg][bcol][0];           \
                const bf16x8 yl = *(const bf16x8*)&Bl[kg][bcol][0];           \
                acc[n] = __builtin_amdgcn_mfma_f32_32x32x16_bf16(xh, yh, acc[n], 0, 0, 0); \
                acc[n] = __builtin_amdgcn_mfma_f32_32x32x16_bf16(xh, yl, acc[n], 0, 0, 0); \
                acc[n] = __builtin_amdgcn_mfma_f32_32x32x16_bf16(xl, yh, acc[n], 0, 0, 0); \
            }                                                                 \
        }

    // prime the 2-deep pipe
    K1_LOAD(aU0, aV0, pB00, pB01, pB02, pB03, ks);
    K1_LOAD(aU1, aV1, pB10, pB11, pB12, pB13, ks + 1);

    const int ke = ks + K1_KI;
    for (int kt = ks; kt < ke; kt += 2) {
        // ---- even iter: consume set0 ----
        K1_STAGE(aU0, aV0, pB00, pB01, pB02, pB03);
        __syncthreads();
        if (kt + 2 < ke) K1_LOAD(aU0, aV0, pB00, pB01, pB02, pB03, kt + 2);
        K1_MFMA();
        __syncthreads();
        // ---- odd iter: consume set1 ----
        K1_STAGE(aU1, aV1, pB10, pB11, pB12, pB13);
        __syncthreads();
        if (kt + 3 < ke) K1_LOAD(aU1, aV1, pB10, pB11, pB12, pB13, kt + 3);
        K1_MFMA();
        __syncthreads();
    }
    #undef K1_STAGE
    #undef K1_LOAD
    #undef K1_MFMA

    // epilogue: per-split plain stores (nbuf==4) or atomic accumulate (nbuf==1)
    float* hout = h + (nbuf == 4 ? (size_t)s * HSTRIDE : 0);
    if (nbuf == 4) {
        #pragma unroll
        for (int n = 0; n < 2; ++n) {
            const int colg = n0 + wc * 64 + n * 32 + l31;
            #pragma unroll
            for (int j = 0; j < 16; ++j) {
                const int row = (j & 3) + 8 * (j >> 2) + 4 * lhi;
                const int i = i0 + wr * 32 + row;
                if (i < MAXN)
                    hout[((size_t)b * MAXN + i) * MIDD + colg] = acc[n][j];
            }
        }
    } else {
        #pragma unroll
        for (int n = 0; n < 2; ++n) {
            const int colg = n0 + wc * 64 + n * 32 + l31;
            #pragma unroll
            for (int j = 0; j < 16; ++j) {
                const int row = (j & 3) + 8 * (j >> 2) + 4 * lhi;
                const int i = i0 + wr * 32 + row;
                if (i < MAXN)
                    atomicAdd(&hout[((size_t)b * MAXN + i) * MIDD + colg], acc[n][j]);
            }
        }
    }
}

// ---------------------------------------------------------------------------
// K2: fused split-K reduce + bias+relu + GEMM2 + bias + log-softmax + NLL
// + argmax. Staging sums nbuf split buffers then applies relu(x + b1).
// ---------------------------------------------------------------------------
__global__ __launch_bounds__(256, 2)
void k2_head(const float* __restrict__ h, const float* __restrict__ b1,
             const int* __restrict__ rels, const int* __restrict__ rels_pos,
             const float* __restrict__ W2, const float* __restrict__ b2,
             float* __restrict__ out, float* __restrict__ partials, int nbuf)
{
    const int b   = blockIdx.y;
    const int i0  = blockIdx.x * 16;
    const int num = rels_pos[2 * b + 1];
    const int tid = threadIdx.x;
    const int blk = blockIdx.y * gridDim.x + blockIdx.x;

    if (tid < 16) {                              // masked rows: pred = label = -1
        const int i = i0 + tid;
        if (i < MAXN && i >= num) {
            out[1 + b * MAXN + i] = -1.0f;
            out[1 + BB * MAXN + b * MAXN + i] = -1.0f;
        }
    }
    if (i0 >= num) { if (tid == 0) partials[blk] = 0.f; return; }

    __shared__ __align__(16) float hs[MIDD][16]; // [k][row], 49 KB
    __shared__ float wave_nll[4];

    {
        const int row = tid & 15;
        const int kc0 = (tid >> 4) * 4;
        const int hrow_i = min(i0 + row, MAXN - 1);
        const size_t off0 = ((size_t)b * MAXN + hrow_i) * MIDD;
        #pragma unroll
        for (int j = 0; j < 12; ++j) {
            const int k = kc0 + j * 64;
            float4 v = *(const float4*)(h + off0 + k);
            if (nbuf == 4) {
                const float4 v1 = *(const float4*)(h + HSTRIDE     + off0 + k);
                const float4 v2 = *(const float4*)(h + 2 * HSTRIDE + off0 + k);
                const float4 v3 = *(const float4*)(h + 3 * HSTRIDE + off0 + k);
                v.x += v1.x + v2.x + v3.x;
                v.y += v1.y + v2.y + v3.y;
                v.z += v1.z + v2.z + v3.z;
                v.w += v1.w + v2.w + v3.w;
            }
            const float4 bb = *(const float4*)(b1 + k);
            hs[k + 0][row] = fmaxf(v.x + bb.x, 0.f);
            hs[k + 1][row] = fmaxf(v.y + bb.y, 0.f);
            hs[k + 2][row] = fmaxf(v.z + bb.z, 0.f);
            hs[k + 3][row] = fmaxf(v.w + bb.w, 0.f);
        }
    }
    __syncthreads();

    const int lane = tid & 63;
    const int wv   = tid >> 6;
    const int c    = lane;
    const bool has2 = (lane + 64) < LBL;
    const int c2   = has2 ? (lane + 64) : (LBL - 1);

    float acc0[4], acc1[4];
    #pragma unroll
    for (int r = 0; r < 4; ++r) { acc0[r] = 0.f; acc1[r] = 0.f; }

    float wA[8], wB[8], nAr[8], nBr[8];
    #pragma unroll
    for (int j = 0; j < 8; ++j) {
        wA[j] = W2[(size_t)j * LBL + c];
        wB[j] = W2[(size_t)j * LBL + c2];
    }
    for (int kbase = 0; kbase < MIDD; kbase += 8) {
        const bool more = (kbase + 8) < MIDD;
        if (more) {
            #pragma unroll
            for (int j = 0; j < 8; ++j) {
                nAr[j] = W2[(size_t)(kbase + 8 + j) * LBL + c];
                nBr[j] = W2[(size_t)(kbase + 8 + j) * LBL + c2];
            }
        }
        #pragma unroll
        for (int j = 0; j < 8; ++j) {
            const float4 hv = *(const float4*)&hs[kbase + j][wv * 4];
            acc0[0] += hv.x * wA[j]; acc0[1] += hv.y * wA[j];
            acc0[2] += hv.z * wA[j]; acc0[3] += hv.w * wA[j];
            acc1[0] += hv.x * wB[j]; acc1[1] += hv.y * wB[j];
            acc1[2] += hv.z * wB[j]; acc1[3] += hv.w * wB[j];
        }
        if (more) {
            #pragma unroll
            for (int j = 0; j < 8; ++j) { wA[j] = nAr[j]; wB[j] = nBr[j]; }
        }
    }
    const float bc  = b2[c];
    const float bc2 = b2[c2];
    #pragma unroll
    for (int r = 0; r < 4; ++r) { acc0[r] += bc; acc1[r] += bc2; }

    float nll_acc = 0.f;
    #pragma unroll
    for (int r = 0; r < 4; ++r) {
        const int i = i0 + wv * 4 + r;
        if (i >= num || i >= MAXN) continue;
        const float v1 = acc0[r];
        const float v2 = has2 ? acc1[r] : -INFINITY;
        float bv = v1; int bi = c;
        if (v2 > v1) { bv = v2; bi = lane + 64; }
        #pragma unroll
        for (int off = 32; off > 0; off >>= 1) {
            const float ov = __shfl_xor(bv, off);
            const int   oi = __shfl_xor(bi, off);
            if (ov > bv || (ov == bv && oi < bi)) { bv = ov; bi = oi; }
        }
        float se = expf(v1 - bv) + (has2 ? expf(v2 - bv) : 0.f);
        #pragma unroll
        for (int off = 32; off > 0; off >>= 1) se += __shfl_xor(se, off);
        const int lbl = rels[b * MAXN + i];
        float tv = (c == lbl ? v1 : 0.f) + ((has2 && (lane + 64) == lbl) ? v2 : 0.f);
        #pragma unroll
        for (int off = 32; off > 0; off >>= 1) tv += __shfl_xor(tv, off);
        const float nll = bv + logf(se) - tv;
        if (lane == 0) {
            nll_acc += nll;
            out[1 + b * MAXN + i] = (float)bi;
            out[1 + BB * MAXN + b * MAXN + i] = (float)lbl;
        }
    }
    if (lane == 0) wave_nll[wv] = nll_acc;
    __syncthreads();
    if (tid == 0)
        partials[blk] = wave_nll[0] + wave_nll[1] + wave_nll[2] + wave_nll[3];
}

// ---------------------------------------------------------------------------
// K3: reduce partial NLL sums, divide by mask count, write loss.
// ---------------------------------------------------------------------------
__global__ void k3_final(const float* __restrict__ partials,
                         const int* __restrict__ rels_pos, float* __restrict__ out)
{
    const int lane = threadIdx.x;   // 64 threads
    float v = 0.f;
    for (int idx = lane; idx < K2_XTILES * BB; idx += 64) v += partials[idx];
    #pragma unroll
    for (int off = 32; off > 0; off >>= 1) v += __shfl_xor(v, off);
    float cnt = (lane < BB) ? (float)min(max(rels_pos[2 * lane + 1], 0), MAXN) : 0.f;
    #pragma unroll
    for (int off = 32; off > 0; off >>= 1) cnt += __shfl_xor(cnt, off);
    if (lane == 0) out[0] = v / cnt;
}

extern "C" void kernel_launch(void* const* d_in, const int* in_sizes, int n_in,
                              void* d_out, int out_size, void* d_ws, size_t ws_size,
                              hipStream_t stream)
{
    const float* outs     = (const float*)d_in[0];
    const int*   rels     = (const int*)  d_in[1];
    const int*   rels_pos = (const int*)  d_in[2];
    const float* W1       = (const float*)d_in[3];
    const float* b1       = (const float*)d_in[4];
    const float* W2       = (const float*)d_in[5];
    const float* b2       = (const float*)d_in[6];
    float* out = (float*)d_out;

    // ws layout: [h x nbuf][partials][w1hi][w1lo]
    const size_t need4 = (4 * HSTRIDE + K2_XTILES * BB) * sizeof(float)
                       + 2 * (size_t)W1S_JOBS * 8 * sizeof(ushort);
    const int nbuf = (ws_size >= need4) ? 4 : 1;

    float*  h        = (float*)d_ws;                       // nbuf x 19.66 MB
    float*  partials = h + (size_t)nbuf * HSTRIDE;
    ushort* w1hi     = (ushort*)(partials + K2_XTILES * BB);
    ushort* w1lo     = w1hi + (size_t)W1S_JOBS * 8;

    if (nbuf == 1)   // atomic fallback needs zeroed accumulator
        hipMemsetAsync(h, 0, HSTRIDE * sizeof(float), stream);

    hipLaunchKernelGGL(k0_split, dim3((W1S_JOBS + 255) / 256), dim3(256), 0, stream,
                       W1, w1hi, w1lo);

    hipLaunchKernelGGL(k1_gemm1, dim3(K1_BLOCKS), dim3(256), 0, stream,
                       outs, rels_pos, w1hi, w1lo, h, nbuf);

    dim3 g2(K2_XTILES, BB);                                // (25, 16)
    hipLaunchKernelGGL(k2_head, g2, dim3(256), 0, stream,
                       h, b1, rels, rels_pos, W2, b2, out, partials, nbuf);

    hipLaunchKernelGGL(k3_final, dim3(1), dim3(64), 0, stream, partials, rels_pos, out);
}